// Round 1
// 749.852 us; speedup vs baseline: 1.1287x; 1.1287x over previous
//
#include <hip/hip_runtime.h>
#include <cstdint>
#include <cstddef>

// Better_Transformer: B=16384, IN=4096, P=8, D=512
// out = swish2( blockmm( swish1( blockmm(x*g1+nb1, W1)+b1 )*g3+nb3, W2)+b2 ) + x
//
// R1: FUSED per-partition kernel. Partitions are independent end-to-end, so one
// block owns a 64-row x 512-col slice of one partition and runs GEMM1 -> act ->
// GEMM2 -> act+residual with o1 kept in LDS (never HBM).
//  - Weights read directly from global as MFMA B-fragments (16B/lane, [n][k]
//    layout from wconv). grid=(p, mtile) => blockid%8==p => XCD p keeps its
//    1MB of W1p+W2p L2-resident. NO barriers inside either K-loop.
//  - Phase 1 uses swapped operands mfma(W,X) so o1 frags are n-contiguous per
//    lane -> ds_write_b64 into the (reused) LDS buffer.
//  - 64x512 bf16 LDS tile XOR-swizzled (c ^= (m&7)<<3) both sides: kills the
//    128B-row-stride 16-way bank conflict (2.5e7 conflict cycles in baseline).
//  - 64KB LDS, 8 waves, launch_bounds(512,4) -> 2 blocks/CU.

#define B_ROWS 16384
#define IN_SZ  4096
#define P_PART 8
#define D_DIM  512
#define M_BLK  64

typedef unsigned short ushort_t;
typedef __attribute__((ext_vector_type(8))) short short8;   // 8 x bf16 bits (4 VGPRs)
typedef __attribute__((ext_vector_type(4))) float f32x4;    // MFMA accumulator

__device__ inline unsigned short f2bf(float f) {
  union { float f; unsigned int u; } c; c.f = f;
  unsigned int u = c.u;
  return (unsigned short)((u + 0x7fffu + ((u >> 16) & 1u)) >> 16);  // RNE
}

// swizzled ushort index into a [M_BLK][D_DIM] bf16 LDS tile.
// XOR of bits 3..5 of the column with row bits 0..2 => 16B-granular, spreads
// the 1KB row stride across banks. Same mapping used by every write and read.
__device__ inline int swz(int m, int c) { return m * D_DIM + (c ^ ((m & 7) << 3)); }

// ---------------------------------------------------------------- weight prep
// Wt[p][n][k] = W[p][k][n], fp32 -> bf16. grid (8 ktile, 8 ntile, 16), block 256
__global__ __launch_bounds__(256) void wconv_kernel(const float* __restrict__ w1,
                                                    const float* __restrict__ w2,
                                                    ushort_t* __restrict__ wt1,
                                                    ushort_t* __restrict__ wt2) {
  __shared__ float tile[64][68];  // +4 pad
  const int p = blockIdx.z & 7;
  const float*  src = (blockIdx.z < 8) ? w1 : w2;
  ushort_t*     dst = (blockIdx.z < 8) ? wt1 : wt2;
  const int k0 = blockIdx.x * 64;
  const int n0 = blockIdx.y * 64;
  const int t = threadIdx.x;

  const float* base = src + ((size_t)p * D_DIM + k0) * D_DIM + n0;
#pragma unroll
  for (int i = 0; i < 4; ++i) {
    int f = t + i * 256;          // 0..1023
    int kr = f >> 4;
    int c4 = f & 15;
    float4 v = *(const float4*)(base + (size_t)kr * D_DIM + c4 * 4);
    *(float4*)(&tile[kr][c4 * 4]) = v;
  }
  __syncthreads();
  ushort_t* obase = dst + ((size_t)p * D_DIM + n0) * D_DIM + k0;
#pragma unroll
  for (int i = 0; i < 4; ++i) {
    int f = t + i * 256;
    int nr = f >> 4;
    int kc = (f & 15) * 4;
    unsigned int lo = f2bf(tile[kc + 0][nr]) | ((unsigned int)f2bf(tile[kc + 1][nr]) << 16);
    unsigned int hi = f2bf(tile[kc + 2][nr]) | ((unsigned int)f2bf(tile[kc + 3][nr]) << 16);
    uint2 pk; pk.x = lo; pk.y = hi;
    *(uint2*)(obase + (size_t)nr * D_DIM + kc) = pk;
  }
}

// ---------------------------------------------------------------- fused kernel
// block: p = blockIdx.x (0..7), m0 = blockIdx.y*64. 8 waves; wave wn owns the
// 64-col slice [wn*64, wn*64+64) of the 512 partition columns in both phases.
__global__ __launch_bounds__(512, 4) void fused_kernel(
    const float* __restrict__ x,
    const ushort_t* __restrict__ wt1, const ushort_t* __restrict__ wt2,
    const float* __restrict__ bias1, const float* __restrict__ gamma1,
    const float* __restrict__ beta1,
    const float* __restrict__ bias2, const float* __restrict__ gamma3,
    const float* __restrict__ beta3,
    const float* __restrict__ gain1, const float* __restrict__ nbias1,
    const float* __restrict__ gain3, const float* __restrict__ nbias3,
    float* __restrict__ out) {
  __shared__ __align__(16) ushort_t Xs[M_BLK * D_DIM];  // 64KB; x tile, then o1 tile

  const int t = threadIdx.x;
  const int lane = t & 63, wn = t >> 6;
  const int l15 = lane & 15, quad = lane >> 4;
  const int p  = blockIdx.x;
  const int m0 = blockIdx.y * M_BLK;

  const float g1 = gain1[0], nb1 = nbias1[0];
  const float g3 = gain3[0], nb3 = nbias3[0];

  // ---- stage x[m0:m0+64][p*512:+512] -> bf16(x*g1+nb1), swizzled
  {
    const float* xb = x + (size_t)m0 * IN_SZ + (size_t)p * D_DIM;
#pragma unroll
    for (int i = 0; i < 16; ++i) {
      int g = t + i * 512;             // 0..8191 float4-groups
      int m = g >> 7;                  // 128 groups per row
      int c = (g & 127) * 4;
      float4 v = *(const float4*)(xb + (size_t)m * IN_SZ + c);
      uint2 pk;
      pk.x = f2bf(v.x * g1 + nb1) | ((unsigned int)f2bf(v.y * g1 + nb1) << 16);
      pk.y = f2bf(v.z * g1 + nb1) | ((unsigned int)f2bf(v.w * g1 + nb1) << 16);
      *(uint2*)(&Xs[swz(m, c)]) = pk;
    }
  }
  __syncthreads();

  // ---- phase 1: acc[i][j] = W1-slice x X   (swapped operands)
  // a[i]: W1t[p][n = wn*64 + i*16 + l15][kof..kof+7]  (global, L2-resident)
  // b[j]: Xs [m = j*16 + l15][kof..kof+7]
  // D: (quad*4+r) -> n-within-frag, l15 -> m-within-frag
  f32x4 acc[4][4];
#pragma unroll
  for (int i = 0; i < 4; ++i)
#pragma unroll
    for (int j = 0; j < 4; ++j) acc[i][j] = (f32x4)(0.0f);

  {
    const ushort_t* w1b = wt1 + (size_t)p * D_DIM * D_DIM
                              + (size_t)(wn * 64 + l15) * D_DIM;
#pragma unroll 2
    for (int kt = 0; kt < 8; ++kt) {
#pragma unroll
      for (int kk = 0; kk < 2; ++kk) {
        const int kof = kt * 64 + kk * 32 + quad * 8;
        short8 a[4], b[4];
#pragma unroll
        for (int i = 0; i < 4; ++i)
          a[i] = *(const short8*)(w1b + (size_t)(i * 16) * D_DIM + kof);
#pragma unroll
        for (int j = 0; j < 4; ++j)
          b[j] = *(const short8*)(&Xs[swz(j * 16 + l15, kof)]);
#pragma unroll
        for (int i = 0; i < 4; ++i)
#pragma unroll
          for (int j = 0; j < 4; ++j)
            acc[i][j] = __builtin_amdgcn_mfma_f32_16x16x32_bf16(a[i], b[j], acc[i][j], 0, 0, 0);
      }
    }
  }

  __syncthreads();   // all Xs reads done before overwrite

  // ---- epilogue 1: o1 = swish1(acc + b1)*g3 + nb3 -> bf16 -> Xs (as [m][n])
  // lane holds n = base + quad*4 + {0..3} contiguous -> one ds_write_b64/frag
#pragma unroll
  for (int i = 0; i < 4; ++i) {
    const int n = wn * 64 + i * 16 + quad * 4;
    const int col = p * D_DIM + n;
    const float4 bv = *(const float4*)(bias1 + col);
    const float4 ga = *(const float4*)(gamma1 + col);
    const float4 be = *(const float4*)(beta1 + col);
#pragma unroll
    for (int j = 0; j < 4; ++j) {
      const int m = j * 16 + l15;
      float o[4];
#pragma unroll
      for (int r = 0; r < 4; ++r) {
        float v = acc[i][j][r] + ((const float*)&bv)[r];
        float g = ((const float*)&ga)[r];
        float sg = 1.0f / (1.0f + __expf(-((const float*)&be)[r] * v));
        o[r] = ((g + sg * (1.0f - g)) * v) * g3 + nb3;
      }
      uint2 pk;
      pk.x = f2bf(o[0]) | ((unsigned int)f2bf(o[1]) << 16);
      pk.y = f2bf(o[2]) | ((unsigned int)f2bf(o[3]) << 16);
      *(uint2*)(&Xs[swz(m, n)]) = pk;
    }
  }
  __syncthreads();

  // ---- phase 2: acc2[i][j] = o1 x W2-slice  (normal orientation)
  // a[i]: Xs [m = i*16 + l15][kof..kof+7]
  // b[j]: W2t[p][n = wn*64 + j*16 + l15][kof..kof+7]
  f32x4 acc2[4][4];
#pragma unroll
  for (int i = 0; i < 4; ++i)
#pragma unroll
    for (int j = 0; j < 4; ++j) acc2[i][j] = (f32x4)(0.0f);

  {
    const ushort_t* w2b = wt2 + (size_t)p * D_DIM * D_DIM
                              + (size_t)(wn * 64 + l15) * D_DIM;
#pragma unroll 2
    for (int kt = 0; kt < 8; ++kt) {
#pragma unroll
      for (int kk = 0; kk < 2; ++kk) {
        const int kof = kt * 64 + kk * 32 + quad * 8;
        short8 a[4], b[4];
#pragma unroll
        for (int i = 0; i < 4; ++i)
          a[i] = *(const short8*)(&Xs[swz(i * 16 + l15, kof)]);
#pragma unroll
        for (int j = 0; j < 4; ++j)
          b[j] = *(const short8*)(w2b + (size_t)(j * 16) * D_DIM + kof);
#pragma unroll
        for (int i = 0; i < 4; ++i)
#pragma unroll
          for (int j = 0; j < 4; ++j)
            acc2[i][j] = __builtin_amdgcn_mfma_f32_16x16x32_bf16(a[i], b[j], acc2[i][j], 0, 0, 0);
      }
    }
  }

  // ---- epilogue 2: out = swish2(acc2 + b2) + x   (fp32, coalesced 64B runs)
  const int colg0 = p * D_DIM + wn * 64;
#pragma unroll
  for (int j = 0; j < 4; ++j) {
    const int col = colg0 + j * 16 + l15;
    const float bv = bias2[col], ga = gamma3[col], be = beta3[col];
#pragma unroll
    for (int i = 0; i < 4; ++i) {
      const int r0 = m0 + i * 16 + quad * 4;
#pragma unroll
      for (int r = 0; r < 4; ++r) {
        float v = acc2[i][j][r] + bv;
        float sg = 1.0f / (1.0f + __expf(-be * v));
        float o = (ga + sg * (1.0f - ga)) * v;
        const size_t idx = (size_t)(r0 + r) * IN_SZ + col;
        out[idx] = o + x[idx];
      }
    }
  }
}

// ---------------------------------------------------------------- launch
extern "C" void kernel_launch(void* const* d_in, const int* in_sizes, int n_in,
                              void* d_out, int out_size, void* d_ws, size_t ws_size,
                              hipStream_t stream) {
  const float* x      = (const float*)d_in[0];
  const float* w1     = (const float*)d_in[1];
  const float* b1     = (const float*)d_in[2];
  const float* w2     = (const float*)d_in[3];
  const float* b2     = (const float*)d_in[4];
  const float* gamma1 = (const float*)d_in[5];
  const float* beta1  = (const float*)d_in[6];
  const float* gamma3 = (const float*)d_in[7];
  const float* beta3  = (const float*)d_in[8];
  const float* gain1  = (const float*)d_in[9];
  const float* nbias1 = (const float*)d_in[10];
  const float* gain3  = (const float*)d_in[11];
  const float* nbias3 = (const float*)d_in[12];
  float* out = (float*)d_out;

  // ws layout: Wt1 bf16 (4MB) | Wt2 bf16 (4MB)
  ushort_t* wt1 = (ushort_t*)d_ws;
  ushort_t* wt2 = wt1 + (size_t)P_PART * D_DIM * D_DIM;

  wconv_kernel<<<dim3(8, 8, 16), 256, 0, stream>>>(w1, w2, wt1, wt2);
  // grid.x = p so linear block id % 8 == p: pins partition p's weights to XCD p's L2
  fused_kernel<<<dim3(P_PART, B_ROWS / M_BLK), 512, 0, stream>>>(
      x, wt1, wt2, b1, gamma1, beta1, b2, gamma3, beta3,
      gain1, nbias1, gain3, nbias3, out);
}